// Round 2
// baseline (63244.904 us; speedup 1.0000x reference)
//
#include <hip/hip_runtime.h>
#include <math.h>

#define SCALE_F 0.03125f   // 1/sqrt(1024)

// =====================================================================
// fp32 tiled GEMM: C[M,N] = A[M,K] @ (BT ? B[N,K]^T : B[K,N])
// EPI: 0 = none, 1 = silu
// =====================================================================
template<bool BT, int EPI>
__global__ __launch_bounds__(256) void gemm_nt(const float* __restrict__ A,
                                               const float* __restrict__ Bm,
                                               float* __restrict__ C,
                                               int M, int N, int K) {
  __shared__ float As[32][68];
  __shared__ float Bs[32][68];
  const int tid = threadIdx.x;
  const int n0 = blockIdx.x * 64;
  const int m0 = blockIdx.y * 64;
  const int i0 = (tid >> 4) * 4;
  const int j0 = (tid & 15) * 4;
  float acc[4][4] = {};

  for (int k0 = 0; k0 < K; k0 += 32) {
#pragma unroll
    for (int s = 0; s < 2; ++s) {
      int id = tid + 256 * s;
      int r = id >> 3, c4 = id & 7;
      float4 v = *(const float4*)&A[(size_t)(m0 + r) * K + k0 + c4 * 4];
      As[c4 * 4 + 0][r] = v.x; As[c4 * 4 + 1][r] = v.y;
      As[c4 * 4 + 2][r] = v.z; As[c4 * 4 + 3][r] = v.w;
    }
    if (BT) {
#pragma unroll
      for (int s = 0; s < 2; ++s) {
        int id = tid + 256 * s;
        int r = id >> 3, c4 = id & 7;
        float4 v = *(const float4*)&Bm[(size_t)(n0 + r) * K + k0 + c4 * 4];
        Bs[c4 * 4 + 0][r] = v.x; Bs[c4 * 4 + 1][r] = v.y;
        Bs[c4 * 4 + 2][r] = v.z; Bs[c4 * 4 + 3][r] = v.w;
      }
    } else {
#pragma unroll
      for (int s = 0; s < 2; ++s) {
        int id = tid + 256 * s;
        int kk = id >> 4, c4 = id & 15;
        float4 v = *(const float4*)&Bm[(size_t)(k0 + kk) * N + n0 + c4 * 4];
        *(float4*)&Bs[kk][c4 * 4] = v;
      }
    }
    __syncthreads();
#pragma unroll
    for (int kk = 0; kk < 32; ++kk) {
      float4 a = *(const float4*)&As[kk][i0];
      float4 b = *(const float4*)&Bs[kk][j0];
      float av[4] = {a.x, a.y, a.z, a.w};
      float bv[4] = {b.x, b.y, b.z, b.w};
#pragma unroll
      for (int ii = 0; ii < 4; ++ii)
#pragma unroll
        for (int jj = 0; jj < 4; ++jj)
          acc[ii][jj] = fmaf(av[ii], bv[jj], acc[ii][jj]);
    }
    __syncthreads();
  }

#pragma unroll
  for (int ii = 0; ii < 4; ++ii) {
    float4 v;
    float* vp = (float*)&v;
#pragma unroll
    for (int jj = 0; jj < 4; ++jj) {
      float x = acc[ii][jj];
      if (EPI == 1) x = x / (1.0f + __expf(-x));
      vp[jj] = x;
    }
    *(float4*)&C[(size_t)(m0 + i0 + ii) * N + n0 + j0] = v;
  }
}

// =====================================================================
// Coherent (sc1) helpers: all cross-wg data goes through these.
// =====================================================================
__device__ __forceinline__ float ald(const float* p) {
  return __hip_atomic_load(p, __ATOMIC_RELAXED, __HIP_MEMORY_SCOPE_AGENT);
}
__device__ __forceinline__ void ast(float* p, float v) {
  __hip_atomic_store(p, v, __ATOMIC_RELAXED, __HIP_MEMORY_SCOPE_AGENT);
}
__device__ __forceinline__ int ildi(const int* p) {
  return __hip_atomic_load(p, __ATOMIC_RELAXED, __HIP_MEMORY_SCOPE_AGENT);
}

// Rotated tape addressing: row- and column-direction both conflict-free-ish.
#define TIDX(n, e) ((n) * 64 + (((e) + (n)) & 63))

// =====================================================================
// Batch-local persistent scan: 256 wgs x 512 threads (1 block/CU, 8 waves).
// wg (b = wg>>4, es = wg&15) owns, for batch b only:
//   - rows [E0, E0+64) of BOTH W_h and W_write (E0 = es*64):
//       192 fp32/thread in registers + 64 fp32/thread in LDS (4 thr/row)
//   - tape[b][all 64 n][64-e slice] in LDS (rotated layout)
//   - h slice h[b][E0..E0+64)
// => matvec output IS the slice this wg consumes: no global redistribution,
//    batches fully independent: only 16-wg batch-local syncs.
// NOTE: __launch_bounds__(512, 1) is load-bearing. (512, 2) was honored as
// 2 blocks/CU -> VGPR cap 128 -> wreg[192] spilled to scratch -> 83 GB of
// scratch reads (measured). 1 block/CU gives the 256-VGPR tier.
// Monotone counters: cA[b]=bar[b*16], cB[b]=bar[256+b*16]. No resets.
// =====================================================================
__global__ __launch_bounds__(512, 1) void scan_kernel(
    const float* __restrict__ W_h, const float* __restrict__ W_wr,
    const float* __restrict__ b_h, const float* __restrict__ gate,
    float* __restrict__ wx,       // [B][T][D]; rows overwritten with h*gate
    float* __restrict__ ps_g,     // [B][16][64] score partials
    float* __restrict__ qp_g,     // [B][16]    q = h.wv partials
    float* __restrict__ h_g,      // [B][D] (= d_out h_work_f slot)
    float* __restrict__ tape_out, // [B][64][D]
    int* __restrict__ bar) {
  const int tid = threadIdx.x;
  const int wg  = blockIdx.x;
  const int b   = wg >> 4;
  const int es  = wg & 15;
  const int E0  = es * 64;
  const int wave = tid >> 6;
  const int lane = tid & 63;
  const int row  = tid >> 2;     // matvec: 128 rows (0..63 W_h, 64..127 W_wr)
  const int seg  = tid & 3;      // matvec: 256-col segment of the row
  const int nwr  = tid >> 3;     // tape mapping: slot n
  const int ksb  = tid & 7;      // tape mapping: 8-elem e-block

  __shared__ float4 w_lds[16 * 512];     // 128 KB: cols [192,256) of each row
  __shared__ float  tape_l[64 * 64];     // 16 KB, rotated
  __shared__ float  h_lds[4 * 264];      // staged h[b], seg-padded
  __shared__ float  ws_lds[64], wa_lds[64], attn_lds[64];
  __shared__ float  wv_lds[64], Rh_lds[64], h_own[64], read_lds[64];

  // ---- weight preload: rows E0+ (row&63) of W_h (row<64) / W_wr ----
  const float* Wmat = (row < 64) ? W_h : W_wr;
  const float* wbase = Wmat + (size_t)(E0 + (row & 63)) * 1024 + seg * 256;
  float wreg[192];
#pragma unroll
  for (int i = 0; i < 48; ++i)
    *(float4*)&wreg[4 * i] = *(const float4*)&wbase[4 * i];
#pragma unroll
  for (int i = 0; i < 16; ++i)
    w_lds[i * 512 + tid] = *(const float4*)&wbase[192 + 4 * i];

  for (int i = tid; i < 4096; i += 512) tape_l[i] = 0.0f;

  float bh_r = 0.0f;
  if (wave == 0) bh_r = b_h[E0 + lane];
  __syncthreads();

  int* cA = &bar[b * 16];
  int* cB = &bar[256 + b * 16];

  // ---- prologue: h(1) = tanh(wx0 + b_h); ps (vs tape0=0) = 0 ----
  if (wave == 0) {
    size_t xi = (size_t)b * 1048576 + E0 + lane;
    float hv = tanhf(wx[xi] + bh_r);
    h_own[lane] = hv;
    ast(&h_g[b * 1024 + E0 + lane], hv);
    wx[xi] = hv * gate[xi];                 // output row 0
  }
  if (tid < 64) ast(&ps_g[b * 1024 + es * 64 + tid], 0.0f);
  __syncthreads();
  if (tid == 0) {
    asm volatile("s_waitcnt vmcnt(0) lgkmcnt(0)" ::: "memory");
    atomicAdd(cA, 1);
  }

  for (int j = 1; j <= 1024; ++j) {
    const bool last = (j == 1024);
    // ---- waitA: all 16 wgs of batch b published h(j) + ps ----
    if (tid == 0) {
      while (ildi(cA) < 16 * j) __builtin_amdgcn_s_sleep(1);
    }
    __syncthreads();

    // ---- stage h(j)[b] (2 floats/thread) ----
    {
      int d = tid * 2;
      float v0 = ald(&h_g[b * 1024 + d]);
      float v1 = ald(&h_g[b * 1024 + d + 1]);
      h_lds[(d >> 8) * 264 + (d & 255)]     = v0;
      h_lds[(d >> 8) * 264 + (d & 255) + 1] = v1;
    }
    // ws partial loads: issue early, consume after matvec
    float p0 = ald(&ps_g[b * 1024 + (ksb * 2) * 64 + nwr]);
    float p1 = ald(&ps_g[b * 1024 + (ksb * 2 + 1) * 64 + nwr]);
    // wave0 prefetch of wx/gate row j (plain cached loads)
    float wxv = 0.0f, gv = 0.0f;
    size_t xj = 0;
    if (wave == 0 && !last) {
      xj  = (size_t)b * 1048576 + (size_t)j * 1024 + E0 + lane;
      wxv = wx[xj];
      gv  = gate[xj];
    }
    __syncthreads();

    // ---- matvec: acc = W[row][seg*256 .. +256) . h[seg*256 ..) ----
    float acc = 0.0f;
    {
      const float4* h4 = (const float4*)&h_lds[seg * 264];
#pragma unroll
      for (int ii = 0; ii < 48; ++ii) {
        float4 hh = h4[ii];
        acc = fmaf(wreg[4 * ii + 0], hh.x, acc);
        acc = fmaf(wreg[4 * ii + 1], hh.y, acc);
        acc = fmaf(wreg[4 * ii + 2], hh.z, acc);
        acc = fmaf(wreg[4 * ii + 3], hh.w, acc);
      }
#pragma unroll
      for (int ii = 0; ii < 16; ++ii) {
        float4 hh = h4[48 + ii];
        float4 wl = w_lds[ii * 512 + tid];
        acc = fmaf(wl.x, hh.x, acc);
        acc = fmaf(wl.y, hh.y, acc);
        acc = fmaf(wl.z, hh.z, acc);
        acc = fmaf(wl.w, hh.w, acc);
      }
    }
    // ws reduce: ws[n] = sum over 16 es' partials (raw dot)
    {
      float s = p0 + p1;
      s += __shfl_xor(s, 1);
      s += __shfl_xor(s, 2);
      s += __shfl_xor(s, 4);
      if (ksb == 0) ws_lds[nwr] = s;
    }
    // matvec reduce over 4 segs (adjacent lanes)
    acc += __shfl_xor(acc, 1);
    acc += __shfl_xor(acc, 2);
    if (seg == 0) {
      if (row < 64) Rh_lds[row] = acc;
      else          wv_lds[row - 64] = acc;
    }
    __syncthreads();

    // ---- wave0: wa = softmax(SCALE*ws); publish qp partial; arriveB ----
    if (wave == 0) {
      float s = ws_lds[lane] * SCALE_F;
      float m = s;
#pragma unroll
      for (int off = 1; off < 64; off <<= 1) m = fmaxf(m, __shfl_xor(m, off));
      float ex = __expf(s - m);
      float sum = ex;
#pragma unroll
      for (int off = 1; off < 64; off <<= 1) sum += __shfl_xor(sum, off);
      wa_lds[lane] = ex / sum;
      if (!last) {
        float qp = h_own[lane] * wv_lds[lane];
#pragma unroll
        for (int off = 1; off < 64; off <<= 1) qp += __shfl_xor(qp, off);
        if (lane == 0) {
          ast(&qp_g[b * 16 + es], qp);
          asm volatile("s_waitcnt vmcnt(0)" ::: "memory");
          atomicAdd(cB, 1);
        }
      }
    }
    __syncthreads();

    // ---- tape lerp: tape(j) = tape + wa*(wv - tape) ----
    {
      float wa = wa_lds[nwr];
#pragma unroll
      for (int i = 0; i < 8; ++i) {
        int e = ksb * 8 + i;
        int idx = TIDX(nwr, e);
        float t = tape_l[idx];
        tape_l[idx] = fmaf(wa, wv_lds[e] - t, t);
      }
    }
    if (last) break;

    // ---- wave0: waitB -> q -> rs=(1-wa)ws+wa*q -> attn softmax ----
    if (wave == 0) {
      if (lane == 0) {
        while (ildi(cB) < 16 * j) __builtin_amdgcn_s_sleep(1);
      }
      asm volatile("" ::: "memory");
      float qv = (lane < 16) ? ald(&qp_g[b * 16 + lane]) : 0.0f;
      qv += __shfl_xor(qv, 1);
      qv += __shfl_xor(qv, 2);
      qv += __shfl_xor(qv, 4);
      qv += __shfl_xor(qv, 8);
      qv = __shfl(qv, 0);
      float wsr = ws_lds[lane];
      float rs = fmaf(wa_lds[lane], qv - wsr, wsr) * SCALE_F;
      float m = rs;
#pragma unroll
      for (int off = 1; off < 64; off <<= 1) m = fmaxf(m, __shfl_xor(m, off));
      float ex = __expf(rs - m);
      float sum = ex;
#pragma unroll
      for (int off = 1; off < 64; off <<= 1) sum += __shfl_xor(sum, off);
      attn_lds[lane] = ex / sum;
    }
    __syncthreads();

    // ---- gather: read[e] = sum_n attn[n]*tape(j)[n][e] ----
    {
      int ge = tid >> 3, gn = tid & 7;
      float g = 0.0f;
#pragma unroll
      for (int i = 0; i < 8; ++i) {
        int n = gn * 8 + i;
        g = fmaf(attn_lds[n], tape_l[TIDX(n, ge)], g);
      }
      g += __shfl_xor(g, 1);
      g += __shfl_xor(g, 2);
      g += __shfl_xor(g, 4);
      if (gn == 0) read_lds[ge] = g;
    }
    __syncthreads();

    // ---- h(j+1) = tanh(Rh + wx_j + read + b_h); publish + output ----
    if (wave == 0) {
      float hv = tanhf(Rh_lds[lane] + wxv + read_lds[lane] + bh_r);
      h_own[lane] = hv;
      ast(&h_g[b * 1024 + E0 + lane], hv);
      wx[xj] = hv * gv;
    }
    __syncthreads();

    // ---- ps partials vs updated tape: ps[n] = sum_own_e h(j+1).tape(j) ----
    {
      float s = 0.0f;
#pragma unroll
      for (int i = 0; i < 8; ++i) {
        int e = ksb * 8 + i;
        s = fmaf(h_own[e], tape_l[TIDX(nwr, e)], s);
      }
      s += __shfl_xor(s, 1);
      s += __shfl_xor(s, 2);
      s += __shfl_xor(s, 4);
      if (ksb == 0) ast(&ps_g[b * 1024 + es * 64 + nwr], s);
    }
    __syncthreads();
    if (tid == 0) {
      asm volatile("s_waitcnt vmcnt(0) lgkmcnt(0)" ::: "memory");
      atomicAdd(cA, 1);
    }
  }

  // ---- epilogue: dump final tape slice ----
#pragma unroll
  for (int i = 0; i < 8; ++i) {
    int e = ksb * 8 + i;
    tape_out[(size_t)(b * 64 + nwr) * 1024 + E0 + e] = tape_l[TIDX(nwr, e)];
  }
}

// =====================================================================
extern "C" void kernel_launch(void* const* d_in, const int* in_sizes, int n_in,
                              void* d_out, int out_size, void* d_ws, size_t ws_size,
                              hipStream_t stream) {
  (void)in_sizes; (void)n_in; (void)out_size; (void)ws_size;
  const float* x      = (const float*)d_in[0];
  const float* in_w   = (const float*)d_in[1];
  const float* out_w  = (const float*)d_in[2];
  const float* gate_w = (const float*)d_in[3];
  const float* W_x    = (const float*)d_in[4];
  const float* W_h    = (const float*)d_in[5];
  const float* W_wr   = (const float*)d_in[6];
  const float* b_h    = (const float*)d_in[7];

  float* out  = (float*)d_out;                     // [16][1024][1024]
  float* tape = out + (size_t)16 * 1024 * 1024;    // [16][64][1024]
  float* hfin = tape + (size_t)16 * 64 * 1024;     // [16][1024]

  float* ws = (float*)d_ws;
  // scan-time small buffers overlay M1's region (M1 dead before scan)
  float* ps_g = ws;                  // [16][16][64] = 16384 floats
  float* qp_g = ws + 16384;          // [16][16]     = 256 floats
  int*   bar  = (int*)(ws + 17408);  // 512 ints (cA: [0,256), cB: [256,512))
  float* M1   = ws;                  // [1024][1024]
  float* wx   = ws + (1 << 20);      // [16][1024][1024]

  float* gate = out;                 // park gate in d_out region

  dim3 blk(256);
  gemm_nt<false, 0><<<dim3(16, 16), blk, 0, stream>>>(W_x, in_w, M1, 1024, 1024, 1024);
  gemm_nt<true, 1><<<dim3(16, 256), blk, 0, stream>>>(x, gate_w, gate, 16384, 1024, 1024);
  gemm_nt<true, 0><<<dim3(16, 256), blk, 0, stream>>>(x, M1, wx, 16384, 1024, 1024);
  hipMemsetAsync(bar, 0, 2048, stream);
  scan_kernel<<<256, 512, 0, stream>>>(W_h, W_wr, b_h, gate, wx, ps_g, qp_g,
                                       hfin, tape, bar);
  gemm_nt<true, 0><<<dim3(16, 256), blk, 0, stream>>>(wx, out_w, out, 16384, 1024, 1024);
}

// Round 3
// 59750.958 us; speedup vs baseline: 1.0585x; 1.0585x over previous
//
#include <hip/hip_runtime.h>
#include <math.h>

#define SCALE_F 0.03125f   // 1/sqrt(1024)

// =====================================================================
// fp32 tiled GEMM: C[M,N] = A[M,K] @ (BT ? B[N,K]^T : B[K,N])
// EPI: 0 = none, 1 = silu
// =====================================================================
template<bool BT, int EPI>
__global__ __launch_bounds__(256) void gemm_nt(const float* __restrict__ A,
                                               const float* __restrict__ Bm,
                                               float* __restrict__ C,
                                               int M, int N, int K) {
  __shared__ float As[32][68];
  __shared__ float Bs[32][68];
  const int tid = threadIdx.x;
  const int n0 = blockIdx.x * 64;
  const int m0 = blockIdx.y * 64;
  const int i0 = (tid >> 4) * 4;
  const int j0 = (tid & 15) * 4;
  float acc[4][4] = {};

  for (int k0 = 0; k0 < K; k0 += 32) {
#pragma unroll
    for (int s = 0; s < 2; ++s) {
      int id = tid + 256 * s;
      int r = id >> 3, c4 = id & 7;
      float4 v = *(const float4*)&A[(size_t)(m0 + r) * K + k0 + c4 * 4];
      As[c4 * 4 + 0][r] = v.x; As[c4 * 4 + 1][r] = v.y;
      As[c4 * 4 + 2][r] = v.z; As[c4 * 4 + 3][r] = v.w;
    }
    if (BT) {
#pragma unroll
      for (int s = 0; s < 2; ++s) {
        int id = tid + 256 * s;
        int r = id >> 3, c4 = id & 7;
        float4 v = *(const float4*)&Bm[(size_t)(n0 + r) * K + k0 + c4 * 4];
        Bs[c4 * 4 + 0][r] = v.x; Bs[c4 * 4 + 1][r] = v.y;
        Bs[c4 * 4 + 2][r] = v.z; Bs[c4 * 4 + 3][r] = v.w;
      }
    } else {
#pragma unroll
      for (int s = 0; s < 2; ++s) {
        int id = tid + 256 * s;
        int kk = id >> 4, c4 = id & 15;
        float4 v = *(const float4*)&Bm[(size_t)(k0 + kk) * N + n0 + c4 * 4];
        *(float4*)&Bs[kk][c4 * 4] = v;
      }
    }
    __syncthreads();
#pragma unroll
    for (int kk = 0; kk < 32; ++kk) {
      float4 a = *(const float4*)&As[kk][i0];
      float4 b = *(const float4*)&Bs[kk][j0];
      float av[4] = {a.x, a.y, a.z, a.w};
      float bv[4] = {b.x, b.y, b.z, b.w};
#pragma unroll
      for (int ii = 0; ii < 4; ++ii)
#pragma unroll
        for (int jj = 0; jj < 4; ++jj)
          acc[ii][jj] = fmaf(av[ii], bv[jj], acc[ii][jj]);
    }
    __syncthreads();
  }

#pragma unroll
  for (int ii = 0; ii < 4; ++ii) {
    float4 v;
    float* vp = (float*)&v;
#pragma unroll
    for (int jj = 0; jj < 4; ++jj) {
      float x = acc[ii][jj];
      if (EPI == 1) x = x / (1.0f + __expf(-x));
      vp[jj] = x;
    }
    *(float4*)&C[(size_t)(m0 + i0 + ii) * N + n0 + j0] = v;
  }
}

// =====================================================================
// Coherent (sc1) helpers: all cross-wg data goes through these.
// =====================================================================
__device__ __forceinline__ float ald(const float* p) {
  return __hip_atomic_load(p, __ATOMIC_RELAXED, __HIP_MEMORY_SCOPE_AGENT);
}
__device__ __forceinline__ void ast(float* p, float v) {
  __hip_atomic_store(p, v, __ATOMIC_RELAXED, __HIP_MEMORY_SCOPE_AGENT);
}
__device__ __forceinline__ int ildi(const int* p) {
  return __hip_atomic_load(p, __ATOMIC_RELAXED, __HIP_MEMORY_SCOPE_AGENT);
}

// Rotated tape addressing: row- and column-direction both conflict-free-ish.
#define TIDX(n, e) ((n) * 64 + (((e) + (n)) & 63))

// 48-fold repetition for the register-resident weight slice.
// NOTE: named float4 SSA values, NOT a local array. float wreg[192] was an
// alloca; SROA runs before loop unrolling, saw loop-variant indices, left it
// in scratch -> 83 GB/launch of scratch reloads (measured, VGPR_Count=128).
#define REP48(M) M(0) M(1) M(2) M(3) M(4) M(5) M(6) M(7) M(8) M(9) M(10) \
  M(11) M(12) M(13) M(14) M(15) M(16) M(17) M(18) M(19) M(20) M(21) M(22) \
  M(23) M(24) M(25) M(26) M(27) M(28) M(29) M(30) M(31) M(32) M(33) M(34) \
  M(35) M(36) M(37) M(38) M(39) M(40) M(41) M(42) M(43) M(44) M(45) M(46) M(47)

#define WDECL(i) float4 w##i;
#define WLOAD(i) w##i = *(const float4*)&wbase[4 * (i)];
#define WFMA(i) { float4 hh = h4[(i)]; \
  acc = fmaf(w##i.x, hh.x, acc); acc = fmaf(w##i.y, hh.y, acc); \
  acc = fmaf(w##i.z, hh.z, acc); acc = fmaf(w##i.w, hh.w, acc); }

// =====================================================================
// Batch-local persistent scan: 256 wgs x 512 threads (1 block/CU, 8 waves).
// wg (b = wg>>4, es = wg&15) owns, for batch b only:
//   - rows [E0, E0+64) of BOTH W_h and W_write (E0 = es*64):
//       192 fp32/thread in named-float4 registers + 64 fp32/thread in LDS
//   - tape[b][all 64 n][64-e slice] in LDS (rotated layout)
//   - h slice h[b][E0..E0+64)
// => matvec output IS the slice this wg consumes: no global redistribution,
//    batches fully independent: only 16-wg batch-local syncs.
// amdgpu_waves_per_eu(2,2): 150 KB LDS already forces 1 block/CU = 2 waves/EU;
// this pins the backend's VGPR budget to the 256 tier so the 192 weight regs
// stay resident.
// Monotone counters: cA[b]=bar[b*16], cB[b]=bar[256+b*16]. No resets.
// =====================================================================
__global__ __launch_bounds__(512, 1) __attribute__((amdgpu_waves_per_eu(2, 2)))
void scan_kernel(
    const float* __restrict__ W_h, const float* __restrict__ W_wr,
    const float* __restrict__ b_h, const float* __restrict__ gate,
    float* __restrict__ wx,       // [B][T][D]; rows overwritten with h*gate
    float* __restrict__ ps_g,     // [B][16][64] score partials
    float* __restrict__ qp_g,     // [B][16]    q = h.wv partials
    float* __restrict__ h_g,      // [B][D] (= d_out h_work_f slot)
    float* __restrict__ tape_out, // [B][64][D]
    int* __restrict__ bar) {
  const int tid = threadIdx.x;
  const int wg  = blockIdx.x;
  const int b   = wg >> 4;
  const int es  = wg & 15;
  const int E0  = es * 64;
  const int wave = tid >> 6;
  const int lane = tid & 63;
  const int row  = tid >> 2;     // matvec: 128 rows (0..63 W_h, 64..127 W_wr)
  const int seg  = tid & 3;      // matvec: 256-col segment of the row
  const int nwr  = tid >> 3;     // tape mapping: slot n
  const int ksb  = tid & 7;      // tape mapping: 8-elem e-block

  __shared__ float4 w_lds[16 * 512];     // 128 KB: cols [192,256) of each row
  __shared__ float  tape_l[64 * 64];     // 16 KB, rotated
  __shared__ float  h_lds[4 * 264];      // staged h[b], seg-padded
  __shared__ float  ws_lds[64], wa_lds[64], attn_lds[64];
  __shared__ float  wv_lds[64], Rh_lds[64], h_own[64], read_lds[64];

  // ---- weight preload: rows E0+ (row&63) of W_h (row<64) / W_wr ----
  const float* Wmat = (row < 64) ? W_h : W_wr;
  const float* wbase = Wmat + (size_t)(E0 + (row & 63)) * 1024 + seg * 256;
  REP48(WDECL)
  REP48(WLOAD)
#pragma unroll
  for (int i = 0; i < 16; ++i)
    w_lds[i * 512 + tid] = *(const float4*)&wbase[192 + 4 * i];

  for (int i = tid; i < 4096; i += 512) tape_l[i] = 0.0f;

  float bh_r = 0.0f;
  if (wave == 0) bh_r = b_h[E0 + lane];
  __syncthreads();

  int* cA = &bar[b * 16];
  int* cB = &bar[256 + b * 16];

  // ---- prologue: h(1) = tanh(wx0 + b_h); ps (vs tape0=0) = 0 ----
  if (wave == 0) {
    size_t xi = (size_t)b * 1048576 + E0 + lane;
    float hv = tanhf(wx[xi] + bh_r);
    h_own[lane] = hv;
    ast(&h_g[b * 1024 + E0 + lane], hv);
    wx[xi] = hv * gate[xi];                 // output row 0
  }
  if (tid < 64) ast(&ps_g[b * 1024 + es * 64 + tid], 0.0f);
  __syncthreads();
  if (tid == 0) {
    asm volatile("s_waitcnt vmcnt(0) lgkmcnt(0)" ::: "memory");
    atomicAdd(cA, 1);
  }

  for (int j = 1; j <= 1024; ++j) {
    const bool last = (j == 1024);
    // ---- waitA: all 16 wgs of batch b published h(j) + ps ----
    if (tid == 0) {
      while (ildi(cA) < 16 * j) __builtin_amdgcn_s_sleep(1);
    }
    __syncthreads();

    // ---- stage h(j)[b] (2 floats/thread) ----
    {
      int d = tid * 2;
      float v0 = ald(&h_g[b * 1024 + d]);
      float v1 = ald(&h_g[b * 1024 + d + 1]);
      h_lds[(d >> 8) * 264 + (d & 255)]     = v0;
      h_lds[(d >> 8) * 264 + (d & 255) + 1] = v1;
    }
    // ws partial loads: issue early, consume after matvec
    float p0 = ald(&ps_g[b * 1024 + (ksb * 2) * 64 + nwr]);
    float p1 = ald(&ps_g[b * 1024 + (ksb * 2 + 1) * 64 + nwr]);
    // wave0 prefetch of wx/gate row j (plain cached loads)
    float wxv = 0.0f, gv = 0.0f;
    size_t xj = 0;
    if (wave == 0 && !last) {
      xj  = (size_t)b * 1048576 + (size_t)j * 1024 + E0 + lane;
      wxv = wx[xj];
      gv  = gate[xj];
    }
    __syncthreads();

    // ---- matvec: acc = W[row][seg*256 .. +256) . h[seg*256 ..) ----
    float acc = 0.0f;
    {
      const float4* h4 = (const float4*)&h_lds[seg * 264];
      REP48(WFMA)
#pragma unroll
      for (int ii = 0; ii < 16; ++ii) {
        float4 hh = h4[48 + ii];
        float4 wl = w_lds[ii * 512 + tid];
        acc = fmaf(wl.x, hh.x, acc);
        acc = fmaf(wl.y, hh.y, acc);
        acc = fmaf(wl.z, hh.z, acc);
        acc = fmaf(wl.w, hh.w, acc);
      }
    }
    // ws reduce: ws[n] = sum over 16 es' partials (raw dot)
    {
      float s = p0 + p1;
      s += __shfl_xor(s, 1);
      s += __shfl_xor(s, 2);
      s += __shfl_xor(s, 4);
      if (ksb == 0) ws_lds[nwr] = s;
    }
    // matvec reduce over 4 segs (adjacent lanes)
    acc += __shfl_xor(acc, 1);
    acc += __shfl_xor(acc, 2);
    if (seg == 0) {
      if (row < 64) Rh_lds[row] = acc;
      else          wv_lds[row - 64] = acc;
    }
    __syncthreads();

    // ---- wave0: wa = softmax(SCALE*ws); publish qp partial; arriveB ----
    if (wave == 0) {
      float s = ws_lds[lane] * SCALE_F;
      float m = s;
#pragma unroll
      for (int off = 1; off < 64; off <<= 1) m = fmaxf(m, __shfl_xor(m, off));
      float ex = __expf(s - m);
      float sum = ex;
#pragma unroll
      for (int off = 1; off < 64; off <<= 1) sum += __shfl_xor(sum, off);
      wa_lds[lane] = ex / sum;
      if (!last) {
        float qp = h_own[lane] * wv_lds[lane];
#pragma unroll
        for (int off = 1; off < 64; off <<= 1) qp += __shfl_xor(qp, off);
        if (lane == 0) {
          ast(&qp_g[b * 16 + es], qp);
          asm volatile("s_waitcnt vmcnt(0)" ::: "memory");
          atomicAdd(cB, 1);
        }
      }
    }
    __syncthreads();

    // ---- tape lerp: tape(j) = tape + wa*(wv - tape) ----
    {
      float wa = wa_lds[nwr];
#pragma unroll
      for (int i = 0; i < 8; ++i) {
        int e = ksb * 8 + i;
        int idx = TIDX(nwr, e);
        float t = tape_l[idx];
        tape_l[idx] = fmaf(wa, wv_lds[e] - t, t);
      }
    }
    if (last) break;

    // ---- wave0: waitB -> q -> rs=(1-wa)ws+wa*q -> attn softmax ----
    if (wave == 0) {
      if (lane == 0) {
        while (ildi(cB) < 16 * j) __builtin_amdgcn_s_sleep(1);
      }
      asm volatile("" ::: "memory");
      float qv = (lane < 16) ? ald(&qp_g[b * 16 + lane]) : 0.0f;
      qv += __shfl_xor(qv, 1);
      qv += __shfl_xor(qv, 2);
      qv += __shfl_xor(qv, 4);
      qv += __shfl_xor(qv, 8);
      qv = __shfl(qv, 0);
      float wsr = ws_lds[lane];
      float rs = fmaf(wa_lds[lane], qv - wsr, wsr) * SCALE_F;
      float m = rs;
#pragma unroll
      for (int off = 1; off < 64; off <<= 1) m = fmaxf(m, __shfl_xor(m, off));
      float ex = __expf(rs - m);
      float sum = ex;
#pragma unroll
      for (int off = 1; off < 64; off <<= 1) sum += __shfl_xor(sum, off);
      attn_lds[lane] = ex / sum;
    }
    __syncthreads();

    // ---- gather: read[e] = sum_n attn[n]*tape(j)[n][e] ----
    {
      int ge = tid >> 3, gn = tid & 7;
      float g = 0.0f;
#pragma unroll
      for (int i = 0; i < 8; ++i) {
        int n = gn * 8 + i;
        g = fmaf(attn_lds[n], tape_l[TIDX(n, ge)], g);
      }
      g += __shfl_xor(g, 1);
      g += __shfl_xor(g, 2);
      g += __shfl_xor(g, 4);
      if (gn == 0) read_lds[ge] = g;
    }
    __syncthreads();

    // ---- h(j+1) = tanh(Rh + wx_j + read + b_h); publish + output ----
    if (wave == 0) {
      float hv = tanhf(Rh_lds[lane] + wxv + read_lds[lane] + bh_r);
      h_own[lane] = hv;
      ast(&h_g[b * 1024 + E0 + lane], hv);
      wx[xj] = hv * gv;
    }
    __syncthreads();

    // ---- ps partials vs updated tape: ps[n] = sum_own_e h(j+1).tape(j) ----
    {
      float s = 0.0f;
#pragma unroll
      for (int i = 0; i < 8; ++i) {
        int e = ksb * 8 + i;
        s = fmaf(h_own[e], tape_l[TIDX(nwr, e)], s);
      }
      s += __shfl_xor(s, 1);
      s += __shfl_xor(s, 2);
      s += __shfl_xor(s, 4);
      if (ksb == 0) ast(&ps_g[b * 1024 + es * 64 + nwr], s);
    }
    __syncthreads();
    if (tid == 0) {
      asm volatile("s_waitcnt vmcnt(0) lgkmcnt(0)" ::: "memory");
      atomicAdd(cA, 1);
    }
  }

  // ---- epilogue: dump final tape slice ----
#pragma unroll
  for (int i = 0; i < 8; ++i) {
    int e = ksb * 8 + i;
    tape_out[(size_t)(b * 64 + nwr) * 1024 + E0 + e] = tape_l[TIDX(nwr, e)];
  }
}

// =====================================================================
extern "C" void kernel_launch(void* const* d_in, const int* in_sizes, int n_in,
                              void* d_out, int out_size, void* d_ws, size_t ws_size,
                              hipStream_t stream) {
  (void)in_sizes; (void)n_in; (void)out_size; (void)ws_size;
  const float* x      = (const float*)d_in[0];
  const float* in_w   = (const float*)d_in[1];
  const float* out_w  = (const float*)d_in[2];
  const float* gate_w = (const float*)d_in[3];
  const float* W_x    = (const float*)d_in[4];
  const float* W_h    = (const float*)d_in[5];
  const float* W_wr   = (const float*)d_in[6];
  const float* b_h    = (const float*)d_in[7];

  float* out  = (float*)d_out;                     // [16][1024][1024]
  float* tape = out + (size_t)16 * 1024 * 1024;    // [16][64][1024]
  float* hfin = tape + (size_t)16 * 64 * 1024;     // [16][1024]

  float* ws = (float*)d_ws;
  // scan-time small buffers overlay M1's region (M1 dead before scan)
  float* ps_g = ws;                  // [16][16][64] = 16384 floats
  float* qp_g = ws + 16384;          // [16][16]     = 256 floats
  int*   bar  = (int*)(ws + 17408);  // 512 ints (cA: [0,256), cB: [256,512))
  float* M1   = ws;                  // [1024][1024]
  float* wx   = ws + (1 << 20);      // [16][1024][1024]

  float* gate = out;                 // park gate in d_out region

  dim3 blk(256);
  gemm_nt<false, 0><<<dim3(16, 16), blk, 0, stream>>>(W_x, in_w, M1, 1024, 1024, 1024);
  gemm_nt<true, 1><<<dim3(16, 256), blk, 0, stream>>>(x, gate_w, gate, 16384, 1024, 1024);
  gemm_nt<true, 0><<<dim3(16, 256), blk, 0, stream>>>(x, M1, wx, 16384, 1024, 1024);
  hipMemsetAsync(bar, 0, 2048, stream);
  scan_kernel<<<256, 512, 0, stream>>>(W_h, W_wr, b_h, gate, wx, ps_g, qp_g,
                                       hfin, tape, bar);
  gemm_nt<true, 0><<<dim3(16, 256), blk, 0, stream>>>(wx, out_w, out, 16384, 1024, 1024);
}